// Round 19
// baseline (319.415 us; speedup 1.0000x reference)
//
#include <hip/hip_runtime.h>

typedef unsigned short u16;
typedef _Float16 f16x8 __attribute__((ext_vector_type(8)));
typedef u16 u16x8 __attribute__((ext_vector_type(8)));
typedef u16 u16x4 __attribute__((ext_vector_type(4)));
typedef float f32x4 __attribute__((ext_vector_type(4)));

#define NTOK 16384
#define CCH 512
#define SXN ((long)CCH * NTOK)      // x/out batch stride (f32 elems)
#define SQK (512L * NTOK)           // (512,N)/(N,512) u16 batch stride
#define SQP (1024L * NTOK)          // qkpre16 batch stride (u16 elems)
#define SAR 32768L                  // att_raw batch stride (f32)
#define SMB (512L * 512)            // Mb batch stride (u16)

__device__ __forceinline__ float h2f(u16 u) {
  _Float16 h = *(_Float16*)&u; return (float)h;
}
__device__ __forceinline__ u16 f2h(float f) {
  _Float16 h = (_Float16)f; return *(u16*)&h;
}
__device__ __forceinline__ void split2(float v, u16& hi, u16& lo) {
  hi = f2h(v); lo = f2h(v - h2f(hi));
}
// LDS bank-conflict swizzle: XOR 16B-slot index with low 3 row bits (T2/G4).
__device__ __forceinline__ int swz(int row, int ko) { return ko ^ ((row & 7) << 3); }

// k2 LDS swizzle (bijective): logical slot s (0..31) of row r ->
// ps = (((s>>2)+r)&7) | ((s&3)<<3). Conflict-free compute reads.
__device__ __forceinline__ int k2swz(int r, int x) {
  int s = x >> 2, e = x & 3;
  int ps = (((s >> 2) + r) & 7) | ((s & 3) << 3);
  return r * 128 + (ps << 2) + e;
}

// ---------- K0: x (C,N) f32 -> xT (N,C) f16, 64x64 tiles ----------
__global__ __launch_bounds__(256) void k0_transpose(
    const float* __restrict__ x, u16* __restrict__ xh) {
  __shared__ float ld[64][65];
  const long bz = blockIdx.z;
  x += bz * SXN; xh += bz * SQK;
  const int t = threadIdx.x;
  const int n0 = blockIdx.x * 64, c0 = blockIdx.y * 64;
#pragma unroll
  for (int j = 0; j < 4; ++j) {
    int idx = t + 256 * j;
    int cl = idx >> 4, ns = (idx & 15) * 4;
    float4 v = *(const float4*)(x + (long)(c0 + cl) * NTOK + n0 + ns);
    ld[cl][ns] = v.x; ld[cl][ns + 1] = v.y; ld[cl][ns + 2] = v.z; ld[cl][ns + 3] = v.w;
  }
  __syncthreads();
#pragma unroll
  for (int j = 0; j < 4; ++j) {
    int idx = t + 256 * j;
    int nl = idx >> 4, cs = (idx & 15) * 4;
    u16x4 h;
#pragma unroll
    for (int e = 0; e < 4; ++e) h[e] = f2h(ld[cs + e][nl]);
    *(u16x4*)(xh + (long)(n0 + nl) * CCH + c0 + cs) = h;
  }
}

// ---------- K0b: w_qkv f32 -> whi/wlo ----------
__global__ __launch_bounds__(256) void k0_cvt_w(const float* __restrict__ a,
                                                u16* __restrict__ oh,
                                                u16* __restrict__ ol) {
  int i = blockIdx.x * 256 + threadIdx.x;
  const float4 v = ((const float4*)a)[i];
  u16 h0, l0, h1, l1, h2, l2, h3, l3;
  split2(v.x, h0, l0); split2(v.y, h1, l1);
  split2(v.z, h2, l2); split2(v.w, h3, l3);
  ((unsigned long long*)oh)[i] = (unsigned long long)h0 | ((unsigned long long)h1 << 16)
                               | ((unsigned long long)h2 << 32) | ((unsigned long long)h3 << 48);
  ((unsigned long long*)ol)[i] = (unsigned long long)l0 | ((unsigned long long)l1 << 16)
                               | ((unsigned long long)l2 << 32) | ((unsigned long long)l3 << 48);
}

__device__ __forceinline__ void storeC(u16* p, float v) { *p = f2h(v); }
__device__ __forceinline__ void storeC(float* p, float v) { *p = v; }

// ---------- single-precision GEMM: C[M,N] = A[M,K]*B[N,K]^T (+bias), K=512
template <typename OutT, bool BIAS_ROW, int GRP, bool GRP_IS_M>
__global__ __launch_bounds__(256) void gemm_bt(
    const u16* __restrict__ A, const u16* __restrict__ B, OutT* __restrict__ C,
    const float* __restrict__ bias, int ldc, long sA, long sB, long sC) {
  const int K = 512;
  __shared__ __align__(16) u16 lA[128 * 64];
  __shared__ __align__(16) u16 lB[128 * 64];
  const long bz = blockIdx.z;
  A += bz * sA; B += bz * sB; C += bz * sC;
  const int t = threadIdx.x;
  const int lane = t & 63, w = t >> 6;
  const int wm = w & 1, wn = w >> 1;
  const int fx = blockIdx.x, fy = blockIdx.y;
  const int gg = fy & (GRP - 1);
  const int go = fx + 8 * (fy / GRP);
  const int bm = (GRP_IS_M ? gg : go) * 128;
  const int bn = (GRP_IS_M ? go : gg) * 128;
  const f32x4 zero4 = {0.f, 0.f, 0.f, 0.f};
  f32x4 acc[4][4];
#pragma unroll
  for (int i = 0; i < 4; ++i)
#pragma unroll
    for (int j = 0; j < 4; ++j) acc[i][j] = zero4;

  for (int kt = 0; kt < K; kt += 64) {
    u16x8 ra[4], rb[4];
#pragma unroll
    for (int j = 0; j < 4; ++j) {
      int idx = t + 256 * j;
      int row = idx >> 3, ko = (idx & 7) << 3;
      ra[j] = *(const u16x8*)(A + (long)(bm + row) * K + kt + ko);
      rb[j] = *(const u16x8*)(B + (long)(bn + row) * K + kt + ko);
    }
    __syncthreads();
#pragma unroll
    for (int j = 0; j < 4; ++j) {
      int idx = t + 256 * j;
      int row = idx >> 3, ko = (idx & 7) << 3;
      *(u16x8*)(&lA[row * 64 + swz(row, ko)]) = ra[j];
      *(u16x8*)(&lB[row * 64 + swz(row, ko)]) = rb[j];
    }
    __syncthreads();
#pragma unroll
    for (int kk = 0; kk < 2; ++kk) {
      f16x8 af[4], bfr[4];
#pragma unroll
      for (int f = 0; f < 4; ++f) {
        int ar = wm * 64 + f * 16 + (lane & 15);
        int br = wn * 64 + f * 16 + (lane & 15);
        int ko = kk * 32 + (lane >> 4) * 8;
        af[f]  = *(const f16x8*)(&lA[ar * 64 + swz(ar, ko)]);
        bfr[f] = *(const f16x8*)(&lB[br * 64 + swz(br, ko)]);
      }
#pragma unroll
      for (int i = 0; i < 4; ++i)
#pragma unroll
        for (int jj = 0; jj < 4; ++jj)
          acc[i][jj] = __builtin_amdgcn_mfma_f32_16x16x32_f16(af[i], bfr[jj], acc[i][jj], 0, 0, 0);
    }
  }
#pragma unroll
  for (int i = 0; i < 4; ++i) {
    const int r0 = bm + wm * 64 + i * 16 + (lane >> 4) * 4;
#pragma unroll
    for (int jj = 0; jj < 4; ++jj) {
      const int c0 = bn + wn * 64 + jj * 16 + (lane & 15);
      const float bcol = BIAS_ROW ? 0.f : bias[c0];
#pragma unroll
      for (int r = 0; r < 4; ++r) {
        float v = acc[i][jj][r] + (BIAS_ROW ? bias[r0 + r] : bcol);
        storeC(&C[(long)(r0 + r) * ldc + c0], v);
      }
    }
  }
}

// ---------- split GEMM: qkpre f16 = (Ah+Al)[M,K]*Bh[N,K]^T + bias[row]
// W split (hh + lh: W error is SYSTEMATIC, must be corrected); x single-f16
// and f16 output (random-category error, averages over N).
// Ah staged via LDS; Al (L2-resident) fragments direct global->VGPR.
__global__ __launch_bounds__(256) void gemm_split(
    const u16* __restrict__ Ah, const u16* __restrict__ Al,
    const u16* __restrict__ Bh,
    u16* __restrict__ C, const float* __restrict__ bias, int ldc) {
  const int K = 512;
  __shared__ __align__(16) u16 lAh[128 * 64];
  __shared__ __align__(16) u16 lBh[128 * 64];
  const long bz = blockIdx.z;
  Bh += bz * SQK; C += bz * SQP;
  const int t = threadIdx.x;
  const int lane = t & 63, w = t >> 6;
  const int wm = w & 1, wn = w >> 1;
  const int fx = blockIdx.x, fy = blockIdx.y;        // grid (8, 128, 2)
  const int bm = (fy & 7) * 128;
  const int bn = (fx + ((fy >> 3) << 3)) * 128;
  const f32x4 zero4 = {0.f, 0.f, 0.f, 0.f};
  f32x4 acc[4][4];
#pragma unroll
  for (int i = 0; i < 4; ++i)
#pragma unroll
    for (int j = 0; j < 4; ++j) acc[i][j] = zero4;

  const u16* Alp = Al + (long)(bm + wm * 64 + (lane & 15)) * K + ((lane >> 4) << 3);

  for (int kt = 0; kt < K; kt += 64) {
    u16x8 rah[4], rbh[4];
#pragma unroll
    for (int j = 0; j < 4; ++j) {
      int idx = t + 256 * j;
      int row = idx >> 3, ko = (idx & 7) << 3;
      rah[j] = *(const u16x8*)(Ah + (long)(bm + row) * K + kt + ko);
      rbh[j] = *(const u16x8*)(Bh + (long)(bn + row) * K + kt + ko);
    }
    f16x8 afl[2][4];
#pragma unroll
    for (int kk = 0; kk < 2; ++kk)
#pragma unroll
      for (int f = 0; f < 4; ++f)
        afl[kk][f] = *(const f16x8*)(Alp + (long)(f * 16) * K + kt + kk * 32);
    __syncthreads();
#pragma unroll
    for (int j = 0; j < 4; ++j) {
      int idx = t + 256 * j;
      int row = idx >> 3, ko = (idx & 7) << 3;
      *(u16x8*)(&lAh[row * 64 + swz(row, ko)]) = rah[j];
      *(u16x8*)(&lBh[row * 64 + swz(row, ko)]) = rbh[j];
    }
    __syncthreads();
#pragma unroll
    for (int kk = 0; kk < 2; ++kk) {
      f16x8 afh[4], bfh[4];
#pragma unroll
      for (int f = 0; f < 4; ++f) {
        int ar = wm * 64 + f * 16 + (lane & 15);
        int br = wn * 64 + f * 16 + (lane & 15);
        int ko = kk * 32 + (lane >> 4) * 8;
        afh[f] = *(const f16x8*)(&lAh[ar * 64 + swz(ar, ko)]);
        bfh[f] = *(const f16x8*)(&lBh[br * 64 + swz(br, ko)]);
      }
#pragma unroll
      for (int i = 0; i < 4; ++i)
#pragma unroll
        for (int jj = 0; jj < 4; ++jj) {
          acc[i][jj] = __builtin_amdgcn_mfma_f32_16x16x32_f16(afh[i], bfh[jj], acc[i][jj], 0, 0, 0);
          acc[i][jj] = __builtin_amdgcn_mfma_f32_16x16x32_f16(afl[kk][i], bfh[jj], acc[i][jj], 0, 0, 0);
        }
    }
  }
#pragma unroll
  for (int i = 0; i < 4; ++i) {
    const int r0 = bm + wm * 64 + i * 16 + (lane >> 4) * 4;
#pragma unroll
    for (int jj = 0; jj < 4; ++jj) {
      const int c0 = bn + wn * 64 + jj * 16 + (lane & 15);
#pragma unroll
      for (int r = 0; r < 4; ++r) {
        C[(long)(r0 + r) * ldc + c0] = f2h(acc[i][jj][r] + bias[r0 + r]);
      }
    }
  }
}

// ---------- K2qk: channel-major dw 3x3 on f16 input, out q/k f16 + sumsq
__global__ __launch_bounds__(256) void k2_qk(
    const u16* __restrict__ qkpre,
    const float* __restrict__ wdw, const float* __restrict__ bdw,
    u16* __restrict__ qh, u16* __restrict__ kh, float* __restrict__ sumsq) {
  __shared__ float st[34 * 128];
  const long bz = blockIdx.z;
  qkpre += bz * SQP; qh += bz * SQK; kh += bz * SQK; sumsq += bz * 1024;
  const int t = threadIdx.x;
  const int s = blockIdx.x;
  const int ch = blockIdx.y;
  const int y0 = s * 32;
  const u16* src = qkpre + (long)ch * NTOK;
  for (int i = t; i < 1088; i += 256) {
    int r = i >> 5, sl = i & 31;
    int gy = y0 - 1 + r;
    float4 v = {0.f, 0.f, 0.f, 0.f};
    if (gy >= 0 && gy < 128) {
      u16x4 h4 = *(const u16x4*)(src + gy * 128 + sl * 4);
      v.x = h2f(h4[0]); v.y = h2f(h4[1]); v.z = h2f(h4[2]); v.w = h2f(h4[3]);
    }
    *(float4*)(&st[k2swz(r, sl * 4)]) = v;
  }
  float wv[9];
#pragma unroll
  for (int i = 0; i < 9; ++i) wv[i] = wdw[ch * 9 + i];
  const float bi = bdw[ch];
  __syncthreads();
  const int y = t >> 3, xg = t & 7, x16 = xg * 16;
  float r0[18], r1[18], r2[18];
#pragma unroll
  for (int k = 0; k < 4; ++k) {
    *(float4*)(&r0[1 + 4 * k]) = *(const float4*)(&st[k2swz(y + 0, x16 + 4 * k)]);
    *(float4*)(&r1[1 + 4 * k]) = *(const float4*)(&st[k2swz(y + 1, x16 + 4 * k)]);
    *(float4*)(&r2[1 + 4 * k]) = *(const float4*)(&st[k2swz(y + 2, x16 + 4 * k)]);
  }
  r0[0]  = (xg > 0) ? st[k2swz(y + 0, x16 - 1)] : 0.f;
  r1[0]  = (xg > 0) ? st[k2swz(y + 1, x16 - 1)] : 0.f;
  r2[0]  = (xg > 0) ? st[k2swz(y + 2, x16 - 1)] : 0.f;
  r0[17] = (xg < 7) ? st[k2swz(y + 0, x16 + 16)] : 0.f;
  r1[17] = (xg < 7) ? st[k2swz(y + 1, x16 + 16)] : 0.f;
  r2[17] = (xg < 7) ? st[k2swz(y + 2, x16 + 16)] : 0.f;
  u16 oh[16];
  float ss = 0.f;
#pragma unroll
  for (int j = 0; j < 16; ++j) {
    float o = bi;
    o += wv[0] * r0[j] + wv[1] * r0[j + 1] + wv[2] * r0[j + 2];
    o += wv[3] * r1[j] + wv[4] * r1[j + 1] + wv[5] * r1[j + 2];
    o += wv[6] * r2[j] + wv[7] * r2[j + 1] + wv[8] * r2[j + 2];
    ss += o * o;
    oh[j] = f2h(o);
  }
  const bool isq = ch < 512;
  u16* dh = isq ? qh : kh;
  const long o = (long)(isq ? ch : ch - 512) * NTOK + (y0 + y) * 128 + x16;
  *(u16x8*)(dh + o)     = *(u16x8*)&oh[0];
  *(u16x8*)(dh + o + 8) = *(u16x8*)&oh[8];
#pragma unroll
  for (int off = 32; off > 0; off >>= 1) ss += __shfl_xor(ss, off);
  if ((t & 63) == 0) atomicAdd(&sumsq[ch], ss);
}

// ---------- K2v: dw 3x3 single precision for v, out token-major ----------
__global__ __launch_bounds__(256) void k2_v(
    const u16* __restrict__ vpre, const float* __restrict__ wdw,
    const float* __restrict__ bdw, u16* __restrict__ vtm) {
  __shared__ __align__(16) u16 st[3 * 66 * 64];
  const long bz = blockIdx.z;
  vpre += bz * SQK; vtm += bz * SQK;
  const int t = threadIdx.x;
  const int xc = blockIdx.x & 1, cc = blockIdx.x >> 1;
  const int y = blockIdx.y;
  const int c0 = cc * 64;
  for (int i = t; i < 1584; i += 256) {
    int l8 = i & 7, dyxi = i >> 3;
    int dy = dyxi / 66, xi = dyxi - dy * 66;
    int yy = y + dy - 1, xx = xc * 64 + xi - 1;
    u16x8 val = {0, 0, 0, 0, 0, 0, 0, 0};
    if (yy >= 0 && yy < 128 && xx >= 0 && xx < 128)
      val = *(const u16x8*)(vpre + (long)(yy * 128 + xx) * 512 + c0 + l8 * 8);
    *(u16x8*)(&st[dyxi * 64 + l8 * 8]) = val;
  }
  __syncthreads();
  const int ch2 = t & 31;
  const int xq = t >> 5;
  const int cga = 1024 + c0 + 2 * ch2;
  float w0[9], w1[9];
#pragma unroll
  for (int i = 0; i < 9; ++i) { w0[i] = wdw[cga * 9 + i]; w1[i] = wdw[(cga + 1) * 9 + i]; }
  const float bi0 = bdw[cga], bi1 = bdw[cga + 1];
  const int nb = y * 128 + xc * 64;
#pragma unroll
  for (int m = 0; m < 8; ++m) {
    int xl = xq * 8 + m;
    float s0 = bi0, s1 = bi1;
#pragma unroll
    for (int dy = 0; dy < 3; ++dy)
#pragma unroll
      for (int dx = 0; dx < 3; ++dx) {
        unsigned int v2 = *(const unsigned int*)(&st[(dy * 66 + xl + dx) * 64 + 2 * ch2]);
        s0 += w0[dy * 3 + dx] * h2f((u16)(v2 & 0xffffu));
        s1 += w1[dy * 3 + dx] * h2f((u16)(v2 >> 16));
      }
    unsigned int pack = (unsigned int)f2h(s0) | ((unsigned int)f2h(s1) << 16);
    *(unsigned int*)(vtm + (long)(nb + xq * 8 + m) * 512 + c0 + 2 * ch2) = pack;
  }
}

// ---------- K3: att_raw[h] += q_h * k_h^T, single f16 (reg-staged) ----------
__global__ __launch_bounds__(256) void k3_qk(
    const u16* __restrict__ qh, const u16* __restrict__ kh,
    float* __restrict__ att_raw) {
  __shared__ __align__(16) u16 lq[64 * 128];
  __shared__ __align__(16) u16 lk[64 * 128];
  const long bz = blockIdx.z;
  qh += bz * SQK; kh += bz * SQK; att_raw += bz * SAR;
  const int t = threadIdx.x, lane = t & 63, w = t >> 6;
  const int h = blockIdx.y;
  const int n0b = blockIdx.x * 256;
  const u16* qhb = qh + (long)(h * 64) * NTOK;
  const u16* khb = kh + (long)(h * 64) * NTOK;
  const f32x4 zero4 = {0.f, 0.f, 0.f, 0.f};
  f32x4 acc[4] = {zero4, zero4, zero4, zero4};
  for (int ch = 0; ch < 2; ++ch) {
    const int n0 = n0b + ch * 128;
    u16x8 r0[4], r2[4];
#pragma unroll
    for (int j = 0; j < 4; ++j) {
      int idx = t + 256 * j;
      int row = idx >> 4, ko = (idx & 15) << 3;
      long o = (long)row * NTOK + n0 + ko;
      r0[j] = *(const u16x8*)(qhb + o);
      r2[j] = *(const u16x8*)(khb + o);
    }
    __syncthreads();
#pragma unroll
    for (int j = 0; j < 4; ++j) {
      int idx = t + 256 * j;
      int row = idx >> 4, ko = (idx & 15) << 3;
      int sko = swz(row, ko);
      *(u16x8*)(&lq[row * 128 + sko]) = r0[j];
      *(u16x8*)(&lk[row * 128 + sko]) = r2[j];
    }
    __syncthreads();
#pragma unroll
    for (int kk = 0; kk < 4; ++kk) {
      int br = w * 16 + (lane & 15);
      int ko = kk * 32 + (lane >> 4) * 8;
      f16x8 bfh = *(const f16x8*)(&lk[br * 128 + swz(br, ko)]);
#pragma unroll
      for (int f = 0; f < 4; ++f) {
        int ar = f * 16 + (lane & 15);
        f16x8 afh = *(const f16x8*)(&lq[ar * 128 + swz(ar, ko)]);
        acc[f] = __builtin_amdgcn_mfma_f32_16x16x32_f16(afh, bfh, acc[f], 0, 0, 0);
      }
    }
  }
  float* dst = att_raw + h * 64 * 64;
#pragma unroll
  for (int f = 0; f < 4; ++f) {
    int rr = f * 16 + (lane >> 4) * 4;
    int col = w * 16 + (lane & 15);
#pragma unroll
    for (int r = 0; r < 4; ++r) atomicAdd(&dst[(rr + r) * 64 + col], acc[f][r]);
  }
}

// ---------- K4 fused: per (head,batch) softmax(top-42) -> LDS, then M build
__global__ __launch_bounds__(256) void k4_fused(
    const float* __restrict__ att_raw, const float* __restrict__ sumsq,
    const float* __restrict__ scale_p, const float* __restrict__ wproj,
    u16* __restrict__ Mb) {
  __shared__ float al[64][64];
  __shared__ float wl[64][68];
  const int h = blockIdx.x;
  const long bz = blockIdx.y;
  att_raw += bz * SAR + h * 4096; sumsq += bz * 1024; Mb += bz * SMB;
  const int t = threadIdx.x, lane = t & 63, w = t >> 6;
  const float scale = scale_p[0];
  // phase 1: softmax with exact top-42 threshold (same ops as old k4_sm)
  const float nk = fmaxf(sqrtf(sumsq[512 + h * 64 + lane]), 1e-12f);
  for (int rr = 0; rr < 16; ++rr) {
    const int i = w * 16 + rr;
    const float nq = fmaxf(sqrtf(sumsq[h * 64 + i]), 1e-12f);
    float v = att_raw[i * 64 + lane] * scale / (nq * nk);
    int cnt = 0;
    for (int m = 0; m < 64; ++m) {
      float vm = __shfl(v, m);
      cnt += (vm > v || (vm == v && m < lane)) ? 1 : 0;
    }
    unsigned long long ball = __ballot(cnt == 41);
    float thresh = __shfl(v, (int)__builtin_ctzll(ball));
    bool keep = v >= thresh;
    float mx = v;
#pragma unroll
    for (int o = 32; o > 0; o >>= 1) mx = fmaxf(mx, __shfl_xor(mx, o));
    float e = keep ? __expf(v - mx) : 0.f;
    float s = e;
#pragma unroll
    for (int o = 32; o > 0; o >>= 1) s += __shfl_xor(s, o);
    al[i][lane] = e / s;
  }
  __syncthreads();
  // phase 2: M[c, h*64+j] = sum_i wproj[c, h*64+i] * al[i][j], 8 c-blocks
  const int jd4 = (t & 15) * 4, r0 = t >> 4;
  for (int cb = 0; cb < 8; ++cb) {
    const int c0 = cb * 64;
#pragma unroll
    for (int j = 0; j < 4; ++j) {
      int idx = t + 256 * j;
      int r = idx >> 4, c4 = (idx & 15) * 4;
      *(float4*)(&wl[r][c4]) = *(const float4*)(&wproj[(long)(c0 + r) * 512 + h * 64 + c4]);
    }
    __syncthreads();
    f32x4 acc[4];
    const f32x4 zero4 = {0.f, 0.f, 0.f, 0.f};
#pragma unroll
    for (int m = 0; m < 4; ++m) acc[m] = zero4;
#pragma unroll
    for (int i2 = 0; i2 < 64; ++i2) {
      f32x4 a4 = *(const f32x4*)(&al[i2][jd4]);
#pragma unroll
      for (int m = 0; m < 4; ++m) {
        float wv = wl[r0 + m * 16][i2];
        acc[m] += wv * a4;
      }
    }
#pragma unroll
    for (int m = 0; m < 4; ++m) {
      u16x4 p;
#pragma unroll
      for (int e = 0; e < 4; ++e) p[e] = f2h(acc[m][e]);
      *(u16x4*)(Mb + (long)(c0 + r0 + m * 16) * 512 + h * 64 + jd4) = p;
    }
    __syncthreads();
  }
}

extern "C" void kernel_launch(void* const* d_in, const int* in_sizes, int n_in,
                              void* d_out, int out_size, void* d_ws, size_t ws_size,
                              hipStream_t stream) {
  (void)in_sizes; (void)n_in; (void)out_size; (void)ws_size;
  const float* x      = (const float*)d_in[0];
  const float* w_qkv  = (const float*)d_in[1];
  const float* b_qkv  = (const float*)d_in[2];
  const float* w_dw   = (const float*)d_in[3];
  const float* b_dw   = (const float*)d_in[4];
  const float* scale  = (const float*)d_in[5];
  const float* w_proj = (const float*)d_in[6];
  const float* b_proj = (const float*)d_in[7];
  float* out = (float*)d_out;
  char* ws = (char*)d_ws;

  // batched (z=2) workspace, total ~172.5 MB; vpre[2] lives in d_out (32 of
  // 64 MB) — dead before the final GEMM overwrites that region.
  u16* qkpre16  = (u16*)(ws + 0L);            // 2 x (1024,N) f16   67108864
  u16* xT_hi    = (u16*)(ws + 67108864L);     // 2 x (N,512) -> q_hi 33554432
  u16* k_hi     = (u16*)(ws + 100663296L);    // 2 x (512,N)        33554432
  u16* vtm      = (u16*)(ws + 134217728L);    // 2 x (N,512)        33554432
  u16* whi      = (u16*)(ws + 167772160L);    // (1536,512)          1572864
  u16* wlo      = (u16*)(ws + 169345024L);    //                     1572864
  float* sumsq  = (float*)(ws + 170917888L);  // 2 x 1024 f32           8192
  float* att_raw= (float*)(ws + 170926080L);  // 2 x 8*64*64 f32      262144
  u16* Mb       = (u16*)(ws + 171450368L);    // 2 x (512,512)       1048576
  u16* q_hi = xT_hi;
  u16* vpre = (u16*)d_out;                    // 2 x (N,512) f16    33554432

  k0_cvt_w<<<dim3(768), 256, 0, stream>>>(w_qkv, whi, wlo);
  hipMemsetAsync(sumsq, 0, 8192 + 262144, stream);

  k0_transpose<<<dim3(256, 8, 2), 256, 0, stream>>>(x, xT_hi);
  // q,k channels: W-split GEMM -> qkpre f16 channel-major (1024, N)
  gemm_split<<<dim3(8, 128, 2), 256, 0, stream>>>(
      whi, wlo, xT_hi, qkpre16, b_qkv, NTOK);
  // v channels: single GEMM -> vpre (N,512) token-major (scratch in d_out)
  gemm_bt<u16, false, 4, false><<<dim3(8, 64, 2), 256, 0, stream>>>(
      xT_hi, whi + (long)1024 * 512, vpre, b_qkv + 1024, 512,
      SQK, 0L, SQK);
  // depthwise q/k: channel-major strips (xT_hi reused as q_hi output)
  k2_qk<<<dim3(4, 1024, 2), 256, 0, stream>>>(
      qkpre16, w_dw, b_dw, q_hi, k_hi, sumsq);
  k2_v<<<dim3(16, 128, 2), 256, 0, stream>>>(vpre, w_dw, b_dw, vtm);
  // qk^T single f16 (4 blocks/CU)
  k3_qk<<<dim3(64, 8, 2), 256, 0, stream>>>(q_hi, k_hi, att_raw);
  // fused softmax + M build
  k4_fused<<<dim3(8, 2, 1), 256, 0, stream>>>(att_raw, sumsq, scale, w_proj, Mb);
  // out[c][n] = sum_d Mb[c][d] * vtm[n][d] + b_proj[c]  (overwrites vpre)
  gemm_bt<float, true, 4, true><<<dim3(8, 64, 2), 256, 0, stream>>>(
      Mb, vtm, out, b_proj, NTOK, SMB, SQK, SXN);
}

// Round 20
// 261.581 us; speedup vs baseline: 1.2211x; 1.2211x over previous
//
#include <hip/hip_runtime.h>

typedef unsigned short u16;
typedef _Float16 f16x8 __attribute__((ext_vector_type(8)));
typedef u16 u16x8 __attribute__((ext_vector_type(8)));
typedef u16 u16x4 __attribute__((ext_vector_type(4)));
typedef float f32x4 __attribute__((ext_vector_type(4)));

#define NTOK 16384
#define CCH 512
#define SXN ((long)CCH * NTOK)      // x/out batch stride (f32 elems)
#define SQK (512L * NTOK)           // (512,N)/(N,512) u16 batch stride
#define SQP (1024L * NTOK)          // qkpre16 batch stride (u16 elems)
#define SAR 32768L                  // att_raw/att batch stride (f32)
#define SMB (512L * 512)            // Mb batch stride (u16)

__device__ __forceinline__ float h2f(u16 u) {
  _Float16 h = *(_Float16*)&u; return (float)h;
}
__device__ __forceinline__ u16 f2h(float f) {
  _Float16 h = (_Float16)f; return *(u16*)&h;
}
__device__ __forceinline__ void split2(float v, u16& hi, u16& lo) {
  hi = f2h(v); lo = f2h(v - h2f(hi));
}
// LDS bank-conflict swizzle: XOR 16B-slot index with low 3 row bits (T2/G4).
__device__ __forceinline__ int swz(int row, int ko) { return ko ^ ((row & 7) << 3); }

// k2 LDS swizzle (bijective): logical slot s (0..31) of row r ->
// ps = (((s>>2)+r)&7) | ((s&3)<<3). Conflict-free compute reads.
__device__ __forceinline__ int k2swz(int r, int x) {
  int s = x >> 2, e = x & 3;
  int ps = (((s >> 2) + r) & 7) | ((s & 3) << 3);
  return r * 128 + (ps << 2) + e;
}

// ---------- K0: x (C,N) f32 -> xT (N,C) f16, 64x64 tiles ----------
__global__ __launch_bounds__(256) void k0_transpose(
    const float* __restrict__ x, u16* __restrict__ xh) {
  __shared__ float ld[64][65];
  const long bz = blockIdx.z;
  x += bz * SXN; xh += bz * SQK;
  const int t = threadIdx.x;
  const int n0 = blockIdx.x * 64, c0 = blockIdx.y * 64;
#pragma unroll
  for (int j = 0; j < 4; ++j) {
    int idx = t + 256 * j;
    int cl = idx >> 4, ns = (idx & 15) * 4;
    float4 v = *(const float4*)(x + (long)(c0 + cl) * NTOK + n0 + ns);
    ld[cl][ns] = v.x; ld[cl][ns + 1] = v.y; ld[cl][ns + 2] = v.z; ld[cl][ns + 3] = v.w;
  }
  __syncthreads();
#pragma unroll
  for (int j = 0; j < 4; ++j) {
    int idx = t + 256 * j;
    int nl = idx >> 4, cs = (idx & 15) * 4;
    u16x4 h;
#pragma unroll
    for (int e = 0; e < 4; ++e) h[e] = f2h(ld[cs + e][nl]);
    *(u16x4*)(xh + (long)(n0 + nl) * CCH + c0 + cs) = h;
  }
}

// ---------- K0b: w_qkv f32 -> whi/wlo ----------
__global__ __launch_bounds__(256) void k0_cvt_w(const float* __restrict__ a,
                                                u16* __restrict__ oh,
                                                u16* __restrict__ ol) {
  int i = blockIdx.x * 256 + threadIdx.x;
  const float4 v = ((const float4*)a)[i];
  u16 h0, l0, h1, l1, h2, l2, h3, l3;
  split2(v.x, h0, l0); split2(v.y, h1, l1);
  split2(v.z, h2, l2); split2(v.w, h3, l3);
  ((unsigned long long*)oh)[i] = (unsigned long long)h0 | ((unsigned long long)h1 << 16)
                               | ((unsigned long long)h2 << 32) | ((unsigned long long)h3 << 48);
  ((unsigned long long*)ol)[i] = (unsigned long long)l0 | ((unsigned long long)l1 << 16)
                               | ((unsigned long long)l2 << 32) | ((unsigned long long)l3 << 48);
}

__device__ __forceinline__ void storeC(u16* p, float v) { *p = f2h(v); }
__device__ __forceinline__ void storeC(float* p, float v) { *p = v; }

// ---------- single-precision GEMM: C[M,N] = A[M,K]*B[N,K]^T (+bias), K=512
template <typename OutT, bool BIAS_ROW, int GRP, bool GRP_IS_M>
__global__ __launch_bounds__(256) void gemm_bt(
    const u16* __restrict__ A, const u16* __restrict__ B, OutT* __restrict__ C,
    const float* __restrict__ bias, int ldc, long sA, long sB, long sC) {
  const int K = 512;
  __shared__ __align__(16) u16 lA[128 * 64];
  __shared__ __align__(16) u16 lB[128 * 64];
  const long bz = blockIdx.z;
  A += bz * sA; B += bz * sB; C += bz * sC;
  const int t = threadIdx.x;
  const int lane = t & 63, w = t >> 6;
  const int wm = w & 1, wn = w >> 1;
  const int fx = blockIdx.x, fy = blockIdx.y;
  const int gg = fy & (GRP - 1);
  const int go = fx + 8 * (fy / GRP);
  const int bm = (GRP_IS_M ? gg : go) * 128;
  const int bn = (GRP_IS_M ? go : gg) * 128;
  const f32x4 zero4 = {0.f, 0.f, 0.f, 0.f};
  f32x4 acc[4][4];
#pragma unroll
  for (int i = 0; i < 4; ++i)
#pragma unroll
    for (int j = 0; j < 4; ++j) acc[i][j] = zero4;

  for (int kt = 0; kt < K; kt += 64) {
    u16x8 ra[4], rb[4];
#pragma unroll
    for (int j = 0; j < 4; ++j) {
      int idx = t + 256 * j;
      int row = idx >> 3, ko = (idx & 7) << 3;
      ra[j] = *(const u16x8*)(A + (long)(bm + row) * K + kt + ko);
      rb[j] = *(const u16x8*)(B + (long)(bn + row) * K + kt + ko);
    }
    __syncthreads();
#pragma unroll
    for (int j = 0; j < 4; ++j) {
      int idx = t + 256 * j;
      int row = idx >> 3, ko = (idx & 7) << 3;
      *(u16x8*)(&lA[row * 64 + swz(row, ko)]) = ra[j];
      *(u16x8*)(&lB[row * 64 + swz(row, ko)]) = rb[j];
    }
    __syncthreads();
#pragma unroll
    for (int kk = 0; kk < 2; ++kk) {
      f16x8 af[4], bfr[4];
#pragma unroll
      for (int f = 0; f < 4; ++f) {
        int ar = wm * 64 + f * 16 + (lane & 15);
        int br = wn * 64 + f * 16 + (lane & 15);
        int ko = kk * 32 + (lane >> 4) * 8;
        af[f]  = *(const f16x8*)(&lA[ar * 64 + swz(ar, ko)]);
        bfr[f] = *(const f16x8*)(&lB[br * 64 + swz(br, ko)]);
      }
#pragma unroll
      for (int i = 0; i < 4; ++i)
#pragma unroll
        for (int jj = 0; jj < 4; ++jj)
          acc[i][jj] = __builtin_amdgcn_mfma_f32_16x16x32_f16(af[i], bfr[jj], acc[i][jj], 0, 0, 0);
    }
  }
#pragma unroll
  for (int i = 0; i < 4; ++i) {
    const int r0 = bm + wm * 64 + i * 16 + (lane >> 4) * 4;
#pragma unroll
    for (int jj = 0; jj < 4; ++jj) {
      const int c0 = bn + wn * 64 + jj * 16 + (lane & 15);
      const float bcol = BIAS_ROW ? 0.f : bias[c0];
#pragma unroll
      for (int r = 0; r < 4; ++r) {
        float v = acc[i][jj][r] + (BIAS_ROW ? bias[r0 + r] : bcol);
        storeC(&C[(long)(r0 + r) * ldc + c0], v);
      }
    }
  }
}

// ---------- split GEMM: qkpre f16 = (Ah+Al)[M,K]*Bh[N,K]^T + bias[row]
// W split (hh + lh: W error is SYSTEMATIC, must be corrected); x single-f16
// and f16 output (random-category error, averages over N).
// Ah staged via LDS; Al (L2-resident) fragments direct global->VGPR.
__global__ __launch_bounds__(256) void gemm_split(
    const u16* __restrict__ Ah, const u16* __restrict__ Al,
    const u16* __restrict__ Bh,
    u16* __restrict__ C, const float* __restrict__ bias, int ldc) {
  const int K = 512;
  __shared__ __align__(16) u16 lAh[128 * 64];
  __shared__ __align__(16) u16 lBh[128 * 64];
  const long bz = blockIdx.z;
  Bh += bz * SQK; C += bz * SQP;
  const int t = threadIdx.x;
  const int lane = t & 63, w = t >> 6;
  const int wm = w & 1, wn = w >> 1;
  const int fx = blockIdx.x, fy = blockIdx.y;        // grid (8, 128, 2)
  const int bm = (fy & 7) * 128;
  const int bn = (fx + ((fy >> 3) << 3)) * 128;
  const f32x4 zero4 = {0.f, 0.f, 0.f, 0.f};
  f32x4 acc[4][4];
#pragma unroll
  for (int i = 0; i < 4; ++i)
#pragma unroll
    for (int j = 0; j < 4; ++j) acc[i][j] = zero4;

  const u16* Alp = Al + (long)(bm + wm * 64 + (lane & 15)) * K + ((lane >> 4) << 3);

  for (int kt = 0; kt < K; kt += 64) {
    u16x8 rah[4], rbh[4];
#pragma unroll
    for (int j = 0; j < 4; ++j) {
      int idx = t + 256 * j;
      int row = idx >> 3, ko = (idx & 7) << 3;
      rah[j] = *(const u16x8*)(Ah + (long)(bm + row) * K + kt + ko);
      rbh[j] = *(const u16x8*)(Bh + (long)(bn + row) * K + kt + ko);
    }
    f16x8 afl[2][4];
#pragma unroll
    for (int kk = 0; kk < 2; ++kk)
#pragma unroll
      for (int f = 0; f < 4; ++f)
        afl[kk][f] = *(const f16x8*)(Alp + (long)(f * 16) * K + kt + kk * 32);
    __syncthreads();
#pragma unroll
    for (int j = 0; j < 4; ++j) {
      int idx = t + 256 * j;
      int row = idx >> 3, ko = (idx & 7) << 3;
      *(u16x8*)(&lAh[row * 64 + swz(row, ko)]) = rah[j];
      *(u16x8*)(&lBh[row * 64 + swz(row, ko)]) = rbh[j];
    }
    __syncthreads();
#pragma unroll
    for (int kk = 0; kk < 2; ++kk) {
      f16x8 afh[4], bfh[4];
#pragma unroll
      for (int f = 0; f < 4; ++f) {
        int ar = wm * 64 + f * 16 + (lane & 15);
        int br = wn * 64 + f * 16 + (lane & 15);
        int ko = kk * 32 + (lane >> 4) * 8;
        afh[f] = *(const f16x8*)(&lAh[ar * 64 + swz(ar, ko)]);
        bfh[f] = *(const f16x8*)(&lBh[br * 64 + swz(br, ko)]);
      }
#pragma unroll
      for (int i = 0; i < 4; ++i)
#pragma unroll
        for (int jj = 0; jj < 4; ++jj) {
          acc[i][jj] = __builtin_amdgcn_mfma_f32_16x16x32_f16(afh[i], bfh[jj], acc[i][jj], 0, 0, 0);
          acc[i][jj] = __builtin_amdgcn_mfma_f32_16x16x32_f16(afl[kk][i], bfh[jj], acc[i][jj], 0, 0, 0);
        }
    }
  }
#pragma unroll
  for (int i = 0; i < 4; ++i) {
    const int r0 = bm + wm * 64 + i * 16 + (lane >> 4) * 4;
#pragma unroll
    for (int jj = 0; jj < 4; ++jj) {
      const int c0 = bn + wn * 64 + jj * 16 + (lane & 15);
#pragma unroll
      for (int r = 0; r < 4; ++r) {
        C[(long)(r0 + r) * ldc + c0] = f2h(acc[i][jj][r] + bias[r0 + r]);
      }
    }
  }
}

// ---------- K2qk: channel-major dw 3x3 on f16 input, out q/k f16 + sumsq
__global__ __launch_bounds__(256) void k2_qk(
    const u16* __restrict__ qkpre,
    const float* __restrict__ wdw, const float* __restrict__ bdw,
    u16* __restrict__ qh, u16* __restrict__ kh, float* __restrict__ sumsq) {
  __shared__ float st[34 * 128];
  const long bz = blockIdx.z;
  qkpre += bz * SQP; qh += bz * SQK; kh += bz * SQK; sumsq += bz * 1024;
  const int t = threadIdx.x;
  const int s = blockIdx.x;
  const int ch = blockIdx.y;
  const int y0 = s * 32;
  const u16* src = qkpre + (long)ch * NTOK;
  for (int i = t; i < 1088; i += 256) {
    int r = i >> 5, sl = i & 31;
    int gy = y0 - 1 + r;
    float4 v = {0.f, 0.f, 0.f, 0.f};
    if (gy >= 0 && gy < 128) {
      u16x4 h4 = *(const u16x4*)(src + gy * 128 + sl * 4);
      v.x = h2f(h4[0]); v.y = h2f(h4[1]); v.z = h2f(h4[2]); v.w = h2f(h4[3]);
    }
    *(float4*)(&st[k2swz(r, sl * 4)]) = v;
  }
  float wv[9];
#pragma unroll
  for (int i = 0; i < 9; ++i) wv[i] = wdw[ch * 9 + i];
  const float bi = bdw[ch];
  __syncthreads();
  const int y = t >> 3, xg = t & 7, x16 = xg * 16;
  float r0[18], r1[18], r2[18];
#pragma unroll
  for (int k = 0; k < 4; ++k) {
    *(float4*)(&r0[1 + 4 * k]) = *(const float4*)(&st[k2swz(y + 0, x16 + 4 * k)]);
    *(float4*)(&r1[1 + 4 * k]) = *(const float4*)(&st[k2swz(y + 1, x16 + 4 * k)]);
    *(float4*)(&r2[1 + 4 * k]) = *(const float4*)(&st[k2swz(y + 2, x16 + 4 * k)]);
  }
  r0[0]  = (xg > 0) ? st[k2swz(y + 0, x16 - 1)] : 0.f;
  r1[0]  = (xg > 0) ? st[k2swz(y + 1, x16 - 1)] : 0.f;
  r2[0]  = (xg > 0) ? st[k2swz(y + 2, x16 - 1)] : 0.f;
  r0[17] = (xg < 7) ? st[k2swz(y + 0, x16 + 16)] : 0.f;
  r1[17] = (xg < 7) ? st[k2swz(y + 1, x16 + 16)] : 0.f;
  r2[17] = (xg < 7) ? st[k2swz(y + 2, x16 + 16)] : 0.f;
  u16 oh[16];
  float ss = 0.f;
#pragma unroll
  for (int j = 0; j < 16; ++j) {
    float o = bi;
    o += wv[0] * r0[j] + wv[1] * r0[j + 1] + wv[2] * r0[j + 2];
    o += wv[3] * r1[j] + wv[4] * r1[j + 1] + wv[5] * r1[j + 2];
    o += wv[6] * r2[j] + wv[7] * r2[j + 1] + wv[8] * r2[j + 2];
    ss += o * o;
    oh[j] = f2h(o);
  }
  const bool isq = ch < 512;
  u16* dh = isq ? qh : kh;
  const long o = (long)(isq ? ch : ch - 512) * NTOK + (y0 + y) * 128 + x16;
  *(u16x8*)(dh + o)     = *(u16x8*)&oh[0];
  *(u16x8*)(dh + o + 8) = *(u16x8*)&oh[8];
#pragma unroll
  for (int off = 32; off > 0; off >>= 1) ss += __shfl_xor(ss, off);
  if ((t & 63) == 0) atomicAdd(&sumsq[ch], ss);
}

// ---------- K2v: dw 3x3 single precision for v, out token-major ----------
__global__ __launch_bounds__(256) void k2_v(
    const u16* __restrict__ vpre, const float* __restrict__ wdw,
    const float* __restrict__ bdw, u16* __restrict__ vtm) {
  __shared__ __align__(16) u16 st[3 * 66 * 64];
  const long bz = blockIdx.z;
  vpre += bz * SQK; vtm += bz * SQK;
  const int t = threadIdx.x;
  const int xc = blockIdx.x & 1, cc = blockIdx.x >> 1;
  const int y = blockIdx.y;
  const int c0 = cc * 64;
  for (int i = t; i < 1584; i += 256) {
    int l8 = i & 7, dyxi = i >> 3;
    int dy = dyxi / 66, xi = dyxi - dy * 66;
    int yy = y + dy - 1, xx = xc * 64 + xi - 1;
    u16x8 val = {0, 0, 0, 0, 0, 0, 0, 0};
    if (yy >= 0 && yy < 128 && xx >= 0 && xx < 128)
      val = *(const u16x8*)(vpre + (long)(yy * 128 + xx) * 512 + c0 + l8 * 8);
    *(u16x8*)(&st[dyxi * 64 + l8 * 8]) = val;
  }
  __syncthreads();
  const int ch2 = t & 31;
  const int xq = t >> 5;
  const int cga = 1024 + c0 + 2 * ch2;
  float w0[9], w1[9];
#pragma unroll
  for (int i = 0; i < 9; ++i) { w0[i] = wdw[cga * 9 + i]; w1[i] = wdw[(cga + 1) * 9 + i]; }
  const float bi0 = bdw[cga], bi1 = bdw[cga + 1];
  const int nb = y * 128 + xc * 64;
#pragma unroll
  for (int m = 0; m < 8; ++m) {
    int xl = xq * 8 + m;
    float s0 = bi0, s1 = bi1;
#pragma unroll
    for (int dy = 0; dy < 3; ++dy)
#pragma unroll
      for (int dx = 0; dx < 3; ++dx) {
        unsigned int v2 = *(const unsigned int*)(&st[(dy * 66 + xl + dx) * 64 + 2 * ch2]);
        s0 += w0[dy * 3 + dx] * h2f((u16)(v2 & 0xffffu));
        s1 += w1[dy * 3 + dx] * h2f((u16)(v2 >> 16));
      }
    unsigned int pack = (unsigned int)f2h(s0) | ((unsigned int)f2h(s1) << 16);
    *(unsigned int*)(vtm + (long)(nb + xq * 8 + m) * 512 + c0 + 2 * ch2) = pack;
  }
}

// ---------- K3: att_raw[h] += q_h * k_h^T, single f16 (reg-staged) ----------
__global__ __launch_bounds__(256) void k3_qk(
    const u16* __restrict__ qh, const u16* __restrict__ kh,
    float* __restrict__ att_raw) {
  __shared__ __align__(16) u16 lq[64 * 128];
  __shared__ __align__(16) u16 lk[64 * 128];
  const long bz = blockIdx.z;
  qh += bz * SQK; kh += bz * SQK; att_raw += bz * SAR;
  const int t = threadIdx.x, lane = t & 63, w = t >> 6;
  const int h = blockIdx.y;
  const int n0b = blockIdx.x * 256;
  const u16* qhb = qh + (long)(h * 64) * NTOK;
  const u16* khb = kh + (long)(h * 64) * NTOK;
  const f32x4 zero4 = {0.f, 0.f, 0.f, 0.f};
  f32x4 acc[4] = {zero4, zero4, zero4, zero4};
  for (int ch = 0; ch < 2; ++ch) {
    const int n0 = n0b + ch * 128;
    u16x8 r0[4], r2[4];
#pragma unroll
    for (int j = 0; j < 4; ++j) {
      int idx = t + 256 * j;
      int row = idx >> 4, ko = (idx & 15) << 3;
      long o = (long)row * NTOK + n0 + ko;
      r0[j] = *(const u16x8*)(qhb + o);
      r2[j] = *(const u16x8*)(khb + o);
    }
    __syncthreads();
#pragma unroll
    for (int j = 0; j < 4; ++j) {
      int idx = t + 256 * j;
      int row = idx >> 4, ko = (idx & 15) << 3;
      int sko = swz(row, ko);
      *(u16x8*)(&lq[row * 128 + sko]) = r0[j];
      *(u16x8*)(&lk[row * 128 + sko]) = r2[j];
    }
    __syncthreads();
#pragma unroll
    for (int kk = 0; kk < 4; ++kk) {
      int br = w * 16 + (lane & 15);
      int ko = kk * 32 + (lane >> 4) * 8;
      f16x8 bfh = *(const f16x8*)(&lk[br * 128 + swz(br, ko)]);
#pragma unroll
      for (int f = 0; f < 4; ++f) {
        int ar = f * 16 + (lane & 15);
        f16x8 afh = *(const f16x8*)(&lq[ar * 128 + swz(ar, ko)]);
        acc[f] = __builtin_amdgcn_mfma_f32_16x16x32_f16(afh, bfh, acc[f], 0, 0, 0);
      }
    }
  }
  float* dst = att_raw + h * 64 * 64;
#pragma unroll
  for (int f = 0; f < 4; ++f) {
    int rr = f * 16 + (lane >> 4) * 4;
    int col = w * 16 + (lane & 15);
#pragma unroll
    for (int r = 0; r < 4; ++r) atomicAdd(&dst[(rr + r) * 64 + col], acc[f][r]);
  }
}

// ---------- K4: normalize, exact top-42 threshold, softmax ----------
__global__ __launch_bounds__(256) void k4_sm(const float* __restrict__ att_raw,
                                             const float* __restrict__ sumsq,
                                             const float* __restrict__ scale_p,
                                             float* __restrict__ att) {
  const long bz = blockIdx.z;
  att_raw += bz * SAR; sumsq += bz * 1024; att += bz * SAR;
  const int t = threadIdx.x, lane = t & 63, w = t >> 6;
  const int row = blockIdx.x * 4 + w;
  const int hi = row >> 6, i = row & 63;
  const float scale = scale_p[0];
  const float nq = fmaxf(sqrtf(sumsq[hi * 64 + i]), 1e-12f);
  const float nk = fmaxf(sqrtf(sumsq[512 + hi * 64 + lane]), 1e-12f);
  float v = att_raw[(long)row * 64 + lane] * scale / (nq * nk);
  int cnt = 0;
  for (int m = 0; m < 64; ++m) {
    float vm = __shfl(v, m);
    cnt += (vm > v || (vm == v && m < lane)) ? 1 : 0;
  }
  unsigned long long ball = __ballot(cnt == 41);
  float thresh = __shfl(v, (int)__builtin_ctzll(ball));
  bool keep = v >= thresh;
  float mx = v;
#pragma unroll
  for (int o = 32; o > 0; o >>= 1) mx = fmaxf(mx, __shfl_xor(mx, o));
  float e = keep ? __expf(v - mx) : 0.f;
  float s = e;
#pragma unroll
  for (int o = 32; o > 0; o >>= 1) s += __shfl_xor(s, o);
  att[(long)row * 64 + lane] = e / s;
}

// ---------- K4b: M[c,h*64+j] = sum_i w_proj[c,h*64+i]*att[h,i,j] ----------
__global__ __launch_bounds__(256) void k4b_m(const float* __restrict__ att,
                                             const float* __restrict__ wproj,
                                             u16* __restrict__ Mb) {
  __shared__ float wl[64][68];
  __shared__ float al[64][64];
  const long bz = blockIdx.z;
  att += bz * SAR; Mb += bz * SMB;
  const int t = threadIdx.x;
  const int cb = blockIdx.x, h = blockIdx.y;
  const int c0 = cb * 64;
#pragma unroll
  for (int j = 0; j < 4; ++j) {
    int idx = t + 256 * j;
    int r = idx >> 4, c4 = (idx & 15) * 4;
    *(float4*)(&wl[r][c4]) = *(const float4*)(&wproj[(long)(c0 + r) * 512 + h * 64 + c4]);
    *(float4*)(&al[r][c4]) = *(const float4*)(&att[(h * 64 + r) * 64 + c4]);
  }
  __syncthreads();
  const int jd4 = (t & 15) * 4, r0 = t >> 4;
  f32x4 acc[4];
  const f32x4 zero4 = {0.f, 0.f, 0.f, 0.f};
#pragma unroll
  for (int m = 0; m < 4; ++m) acc[m] = zero4;
#pragma unroll
  for (int i2 = 0; i2 < 64; ++i2) {
    f32x4 a4 = *(const f32x4*)(&al[i2][jd4]);
#pragma unroll
    for (int m = 0; m < 4; ++m) {
      float wv = wl[r0 + m * 16][i2];
      acc[m] += wv * a4;
    }
  }
#pragma unroll
  for (int m = 0; m < 4; ++m) {
    u16x4 p;
#pragma unroll
    for (int e = 0; e < 4; ++e) p[e] = f2h(acc[m][e]);
    *(u16x4*)(Mb + (long)(c0 + r0 + m * 16) * 512 + h * 64 + jd4) = p;
  }
}

extern "C" void kernel_launch(void* const* d_in, const int* in_sizes, int n_in,
                              void* d_out, int out_size, void* d_ws, size_t ws_size,
                              hipStream_t stream) {
  (void)in_sizes; (void)n_in; (void)out_size; (void)ws_size;
  const float* x      = (const float*)d_in[0];
  const float* w_qkv  = (const float*)d_in[1];
  const float* b_qkv  = (const float*)d_in[2];
  const float* w_dw   = (const float*)d_in[3];
  const float* b_dw   = (const float*)d_in[4];
  const float* scale  = (const float*)d_in[5];
  const float* w_proj = (const float*)d_in[6];
  const float* b_proj = (const float*)d_in[7];
  float* out = (float*)d_out;
  char* ws = (char*)d_ws;

  // batched (z=2) workspace, total ~172.5 MB; vpre[2] lives in d_out (32 of
  // 64 MB) — dead before the final GEMM overwrites that region.
  u16* qkpre16  = (u16*)(ws + 0L);            // 2 x (1024,N) f16   67108864
  u16* xT_hi    = (u16*)(ws + 67108864L);     // 2 x (N,512) -> q_hi 33554432
  u16* k_hi     = (u16*)(ws + 100663296L);    // 2 x (512,N)        33554432
  u16* vtm      = (u16*)(ws + 134217728L);    // 2 x (N,512)        33554432
  u16* whi      = (u16*)(ws + 167772160L);    // (1536,512)          1572864
  u16* wlo      = (u16*)(ws + 169345024L);    //                     1572864
  float* sumsq  = (float*)(ws + 170917888L);  // 2 x 1024 f32           8192
  float* att_raw= (float*)(ws + 170926080L);  // 2 x 8*64*64 f32      262144
  float* att    = (float*)(ws + 171188224L);  //                      262144
  u16* Mb       = (u16*)(ws + 171450368L);    // 2 x (512,512)       1048576
  u16* q_hi = xT_hi;
  u16* vpre = (u16*)d_out;                    // 2 x (N,512) f16    33554432

  k0_cvt_w<<<dim3(768), 256, 0, stream>>>(w_qkv, whi, wlo);
  hipMemsetAsync(sumsq, 0, 8192 + 262144, stream);

  k0_transpose<<<dim3(256, 8, 2), 256, 0, stream>>>(x, xT_hi);
  // q,k channels: W-split GEMM -> qkpre f16 channel-major (1024, N)
  gemm_split<<<dim3(8, 128, 2), 256, 0, stream>>>(
      whi, wlo, xT_hi, qkpre16, b_qkv, NTOK);
  // v channels: single GEMM -> vpre (N,512) token-major (scratch in d_out)
  gemm_bt<u16, false, 4, false><<<dim3(8, 64, 2), 256, 0, stream>>>(
      xT_hi, whi + (long)1024 * 512, vpre, b_qkv + 1024, 512,
      SQK, 0L, SQK);
  // depthwise q/k: channel-major strips (xT_hi reused as q_hi output)
  k2_qk<<<dim3(4, 1024, 2), 256, 0, stream>>>(
      qkpre16, w_dw, b_dw, q_hi, k_hi, sumsq);
  k2_v<<<dim3(16, 128, 2), 256, 0, stream>>>(vpre, w_dw, b_dw, vtm);
  // qk^T single f16 (4 blocks/CU)
  k3_qk<<<dim3(64, 8, 2), 256, 0, stream>>>(q_hi, k_hi, att_raw);
  k4_sm<<<dim3(128, 1, 2), 256, 0, stream>>>(att_raw, sumsq, scale, att);
  k4b_m<<<dim3(8, 8, 2), 256, 0, stream>>>(att, w_proj, Mb);
  // out[c][n] = sum_d Mb[c][d] * vtm[n][d] + b_proj[c]  (overwrites vpre)
  gemm_bt<float, true, 4, true><<<dim3(8, 64, 2), 256, 0, stream>>>(
      Mb, vtm, out, b_proj, NTOK, SMB, SQK, SXN);
}